// Round 2
// baseline (1411.078 us; speedup 1.0000x reference)
//
#include <hip/hip_runtime.h>

// Problem constants: B=N=256, D=S=1024
// out = [ctx 256*1024 fp32 ; W 256*256*1024 fp32]

typedef _Float16 half8 __attribute__((ext_vector_type(8)));
typedef float floatx16 __attribute__((ext_vector_type(16)));

static __device__ __forceinline__ void split_f32(float x, _Float16& hi, _Float16& lo) {
    _Float16 h = (_Float16)x;
    hi = h;
    lo = (_Float16)(x - (float)h);
}

// ---------------------------------------------------------------------------
// Small GEMM: C[M,N] = A[M,K] @ B, fp32 in, hi/lo fp16 split on BOTH operands
// (3 MFMAs) for near-fp32 accuracy. BT=true: B stored [N,K] (contract fast dim,
// direct staging). BT=false: B stored [K,N] (transpose staging).
// OUT_HILO=false -> write fp32 C. OUT_HILO=true -> write hi/lo fp16 pair.
// Tile 64x64, 256 threads (4 waves as 2x2 of 32x32), BK=32.
// ---------------------------------------------------------------------------
template <bool BT, bool OUT_HILO>
__global__ __launch_bounds__(256, 2) void gemm_small(
    const float* __restrict__ Ag, const float* __restrict__ Bg,
    float* __restrict__ Cf, _Float16* __restrict__ Chi, _Float16* __restrict__ Clo,
    int Kdim, int Ndim)
{
    __shared__ __align__(16) _Float16 AsHi[4 * 64 * 8];
    __shared__ __align__(16) _Float16 AsLo[4 * 64 * 8];
    __shared__ __align__(16) _Float16 BsHi[4 * 64 * 8];
    __shared__ __align__(16) _Float16 BsLo[4 * 64 * 8];

    const int tid  = threadIdx.x;
    const int lane = tid & 63;
    const int wave = tid >> 6;
    const int wy = wave >> 1, wx = wave & 1;
    const int l31 = lane & 31, l5 = lane >> 5;
    const int m0 = blockIdx.y * 64, n0 = blockIdx.x * 64;

    floatx16 acc;
#pragma unroll
    for (int j = 0; j < 16; ++j) acc[j] = 0.0f;

    const int sA_m  = tid >> 2;  // 0..63 (row for A / row-of-B for BT)
    const int sA_kg = tid & 3;   // 0..3
    const int sB_n  = tid & 63;  // NN staging: n (coalesced)
    const int sB_kg = tid >> 6;  // NN staging: kg

    const int nkt = Kdim / 32;
#pragma unroll 1
    for (int kt = 0; kt < nkt; ++kt) {
        __syncthreads();
        {   // stage A chunk [32k x 64m] -> [kg][m][8] hi/lo
            const float* src = Ag + (size_t)(m0 + sA_m) * Kdim + kt * 32 + sA_kg * 8;
            half8 hi, lo;
#pragma unroll
            for (int j = 0; j < 8; ++j) {
                _Float16 h, l;
                split_f32(src[j], h, l);
                hi[j] = h; lo[j] = l;
            }
            *(half8*)&AsHi[(sA_kg * 64 + sA_m) * 8] = hi;
            *(half8*)&AsLo[(sA_kg * 64 + sA_m) * 8] = lo;
        }
        if constexpr (BT) {
            const float* src = Bg + (size_t)(n0 + sA_m) * Kdim + kt * 32 + sA_kg * 8;
            half8 hi, lo;
#pragma unroll
            for (int j = 0; j < 8; ++j) {
                _Float16 h, l;
                split_f32(src[j], h, l);
                hi[j] = h; lo[j] = l;
            }
            *(half8*)&BsHi[(sA_kg * 64 + sA_m) * 8] = hi;
            *(half8*)&BsLo[(sA_kg * 64 + sA_m) * 8] = lo;
        } else {
            const float* src = Bg + (size_t)(kt * 32 + sB_kg * 8) * Ndim + n0 + sB_n;
            half8 hi, lo;
#pragma unroll
            for (int j = 0; j < 8; ++j) {
                _Float16 h, l;
                split_f32(src[(size_t)j * Ndim], h, l);
                hi[j] = h; lo[j] = l;
            }
            *(half8*)&BsHi[(sB_kg * 64 + sB_n) * 8] = hi;
            *(half8*)&BsLo[(sB_kg * 64 + sB_n) * 8] = lo;
        }
        __syncthreads();
#pragma unroll
        for (int ks = 0; ks < 2; ++ks) {
            const int kg = ks * 2 + l5;
            const half8 ah = *(half8*)&AsHi[(kg * 64 + wy * 32 + l31) * 8];
            const half8 al = *(half8*)&AsLo[(kg * 64 + wy * 32 + l31) * 8];
            const half8 bh = *(half8*)&BsHi[(kg * 64 + wx * 32 + l31) * 8];
            const half8 bl = *(half8*)&BsLo[(kg * 64 + wx * 32 + l31) * 8];
            acc = __builtin_amdgcn_mfma_f32_32x32x16_f16(ah, bh, acc, 0, 0, 0);
            acc = __builtin_amdgcn_mfma_f32_32x32x16_f16(ah, bl, acc, 0, 0, 0);
            acc = __builtin_amdgcn_mfma_f32_32x32x16_f16(al, bh, acc, 0, 0, 0);
        }
    }

    // C/D layout (verified): col = lane&31, row = (reg&3) + 8*(reg>>2) + 4*(lane>>5)
#pragma unroll
    for (int reg = 0; reg < 16; ++reg) {
        const int row = m0 + wy * 32 + (reg & 3) + 8 * (reg >> 2) + 4 * l5;
        const int col = n0 + wx * 32 + l31;
        const float v = acc[reg];
        if constexpr (OUT_HILO) {
            _Float16 h, l;
            split_f32(v, h, l);
            Chi[(size_t)row * Ndim + col] = h;
            Clo[(size_t)row * Ndim + col] = l;
        } else {
            Cf[(size_t)row * Ndim + col] = v;
        }
    }
}

// ---------------------------------------------------------------------------
// Fused: per (i, b-tile of 32): logits = (Mhi+Mlo) @ fp16(FV[i])  (2 MFMAs),
// row softmax over d=1024, write W, accumulate ctx[i,d] += W * FV[i,b,d].
//
// Round-2 restructure: 32 b-rows per block (was 64) -> acc[4] = 64 regs/thread
// instead of acc[8] = 128. Round-1 counters showed VGPR(128) + AGPR(128 acc)
// = 256 regs/thread -> ONE 8-wave block per CU (Occupancy 22%) -> every
// barrier/vmcnt drain stalled the whole CU (~170 us traffic-independent cost;
// marginal streaming rate was 5.7 TB/s). With acc[4] + no register prefetch,
// total regs <= 128 -> TWO independent blocks/CU; TLP covers staging latency.
//
// 512 threads = 8 waves, each wave owns 32 rows x 128 d (4 n-tiles).
// XCD-aware swizzle: 8 bt-blocks of each i on the same XCD (private L2),
// dispatched within Dw<=64. Per-XCD resident: 8 i x 8 bt, chunk window ~1 MB.
// ---------------------------------------------------------------------------
__global__ __launch_bounds__(512, 4) void fused_attn(
    const float* __restrict__ FV, const _Float16* __restrict__ Mhi,
    const _Float16* __restrict__ Mlo, float* __restrict__ ctx,
    float* __restrict__ Wout)
{
    __shared__ __align__(16) _Float16 AsHi[2 * 32 * 8];
    __shared__ __align__(16) _Float16 AsLo[2 * 32 * 8];
    __shared__ __align__(16) _Float16 Bs[2 * 1024 * 8];
    __shared__ __align__(16) float red1[32 * 8];
    __shared__ __align__(16) float red2[32 * 8];

    const int tid  = threadIdx.x;
    const int lane = tid & 63;
    const int wave = tid >> 6;          // 0..7 = wx: d-slice of 128 cols
    const int wx = wave;
    const int l31 = lane & 31, l5 = lane >> 5;

    // XCD-aware swizzle: ordinal w -> (i, bt); all 8 bt of an i share one XCD.
    const int w   = blockIdx.x;         // 0..2047
    const int xcd = w & 7;
    const int k   = w >> 3;             // 0..255 (slot within XCD)
    const int i   = (xcd << 5) + (k >> 3);  // 0..255
    const int bt  = k & 7;                  // 0..7

    const float* __restrict__ FVi = FV + (size_t)i * 256 * 1024;

    floatx16 acc[4];
#pragma unroll
    for (int nt = 0; nt < 4; ++nt)
#pragma unroll
        for (int j = 0; j < 16; ++j) acc[nt][j] = 0.0f;

    const int am = tid >> 1, akg = tid & 1;  // A staging (tid < 64): 32 rows x 2 kg

#pragma unroll 1
    for (int kt = 0; kt < 16; ++kt) {
        __syncthreads();
        // ---- stage A chunk: M rows [bt*32 .. +32), k cols [kt*16 .. +16) ----
        if (tid < 64) {
            const half8 h = *(const half8*)(Mhi + (size_t)(bt * 32 + am) * 256 + kt * 16 + akg * 8);
            const half8 l = *(const half8*)(Mlo + (size_t)(bt * 32 + am) * 256 + kt * 16 + akg * 8);
            *(half8*)&AsHi[(akg * 32 + am) * 8] = h;
            *(half8*)&AsLo[(akg * 32 + am) * 8] = l;
        }
        // ---- stage B chunk: FV rows [kt*16 .. +16), all 1024 d, fp32->fp16 ----
        // (direct loads, no reg prefetch: the co-resident block covers latency)
#pragma unroll
        for (int rep = 0; rep < 4; ++rep) {
            const int q8 = rep >> 1;                 // n-group (8 rows)
            const int d  = (rep & 1) * 512 + tid;    // column
            const float* src = FVi + (size_t)(kt * 16 + q8 * 8) * 1024 + d;
            half8 h;
#pragma unroll
            for (int r = 0; r < 8; ++r) h[r] = (_Float16)src[(size_t)r * 1024];
            *(half8*)&Bs[(q8 * 1024 + d) * 8] = h;
        }
        __syncthreads();
        // ---- compute: 4 n-tiles x (hi,lo) MFMA ----
        const half8 ah = *(half8*)&AsHi[(l5 * 32 + l31) * 8];
        const half8 al = *(half8*)&AsLo[(l5 * 32 + l31) * 8];
#pragma unroll
        for (int nt = 0; nt < 4; ++nt) {
            const half8 b = *(half8*)&Bs[(l5 * 1024 + wx * 128 + nt * 32 + l31) * 8];
            acc[nt] = __builtin_amdgcn_mfma_f32_32x32x16_f16(ah, b, acc[nt], 0, 0, 0);
            acc[nt] = __builtin_amdgcn_mfma_f32_32x32x16_f16(al, b, acc[nt], 0, 0, 0);
        }
    }

    // ---- softmax over d (rows span 8 wx waves) ----
    // lane holds: col = wx*128 + nt*32 + l31 ; row = (reg&3)+8*(reg>>2)+4*l5
    {
        float st[16];
#pragma unroll
        for (int reg = 0; reg < 16; ++reg) {
            float v = acc[0][reg];
#pragma unroll
            for (int nt = 1; nt < 4; ++nt) v = fmaxf(v, acc[nt][reg]);
#pragma unroll
            for (int off = 1; off < 32; off <<= 1) v = fmaxf(v, __shfl_xor(v, off));
            st[reg] = v;
        }
        if (l31 == 0) {
#pragma unroll
            for (int reg = 0; reg < 16; ++reg) {
                const int row = (reg & 3) + 8 * (reg >> 2) + 4 * l5;
                red1[row * 8 + wx] = st[reg];
            }
        }
    }
    __syncthreads();
    {
        float st[16];
#pragma unroll
        for (int reg = 0; reg < 16; ++reg) {
            const int row = (reg & 3) + 8 * (reg >> 2) + 4 * l5;
            const float4 a4 = *(const float4*)&red1[row * 8];
            const float4 b4 = *(const float4*)&red1[row * 8 + 4];
            const float rmax = fmaxf(fmaxf(fmaxf(a4.x, a4.y), fmaxf(a4.z, a4.w)),
                                     fmaxf(fmaxf(b4.x, b4.y), fmaxf(b4.z, b4.w)));
            float s = 0.0f;
#pragma unroll
            for (int nt = 0; nt < 4; ++nt) {
                const float p = __expf(acc[nt][reg] - rmax);
                acc[nt][reg] = p;
                s += p;
            }
#pragma unroll
            for (int off = 1; off < 32; off <<= 1) s += __shfl_xor(s, off);
            st[reg] = s;
        }
        if (l31 == 0) {
#pragma unroll
            for (int reg = 0; reg < 16; ++reg) {
                const int row = (reg & 3) + 8 * (reg >> 2) + 4 * l5;
                red2[row * 8 + wx] = st[reg];
            }
        }
    }
    __syncthreads();

    // ---- write W, accumulate context ----
    float csum[4];
#pragma unroll
    for (int nt = 0; nt < 4; ++nt) csum[nt] = 0.0f;

    const int rowbase = bt * 32;
#pragma unroll
    for (int nt = 0; nt < 4; ++nt) {
        const int col = wx * 128 + nt * 32 + l31;
#pragma unroll
        for (int reg = 0; reg < 16; ++reg) {
            const int row = (reg & 3) + 8 * (reg >> 2) + 4 * l5;
            const float4 a4 = *(const float4*)&red2[row * 8];
            const float4 b4 = *(const float4*)&red2[row * 8 + 4];
            const float inv = 1.0f / (a4.x + a4.y + a4.z + a4.w + b4.x + b4.y + b4.z + b4.w);
            const float wv = acc[nt][reg] * inv;
            Wout[((size_t)(i * 256 + rowbase + row)) * 1024 + col] = wv;
            const float fv = FVi[(size_t)(rowbase + row) * 1024 + col];
            csum[nt] += wv * fv;
        }
    }
#pragma unroll
    for (int nt = 0; nt < 4; ++nt) {
        const float v = csum[nt] + __shfl_xor(csum[nt], 32);
        if (l5 == 0)
            atomicAdd(&ctx[(size_t)i * 1024 + wx * 128 + nt * 32 + l31], v);
    }
}

// ---------------------------------------------------------------------------
extern "C" void kernel_launch(void* const* d_in, const int* in_sizes, int n_in,
                              void* d_out, int out_size, void* d_ws, size_t ws_size,
                              hipStream_t stream)
{
    const float* FV    = (const float*)d_in[0];  // [256,256,1024]
    const float* state = (const float*)d_in[1];  // [256,1024]
    const float* Q     = (const float*)d_in[2];  // [1024,1024]
    const float* Km    = (const float*)d_in[3];  // [1024,256]

    float* out = (float*)d_out;
    float* ctx = out;                 // [256,1024]
    float* W   = out + 256 * 1024;    // [256,256,1024]

    char* ws = (char*)d_ws;
    float*    A1  = (float*)ws;                                 // [256,1024] fp32, 1 MB
    _Float16* Mhi = (_Float16*)(ws + (1 << 20));                // [256,256] f16, 128 KB
    _Float16* Mlo = (_Float16*)(ws + (1 << 20) + (1 << 17));    // [256,256] f16, 128 KB

    // ctx accumulated with atomics -> zero it
    (void)hipMemsetAsync(ctx, 0, 256 * 1024 * sizeof(float), stream);

    // A1 = state @ Q^T   (B stored [N,K]: Q[s,t], contract t)
    gemm_small<true, false><<<dim3(16, 4), 256, 0, stream>>>(
        state, Q, A1, nullptr, nullptr, 1024, 1024);

    // M = A1 @ K  -> hi/lo fp16   (B stored [K,N])
    gemm_small<false, true><<<dim3(4, 4), 256, 0, stream>>>(
        A1, Km, nullptr, Mhi, Mlo, 1024, 256);

    // fused logits -> softmax -> W + ctx (XCD-swizzled 1D grid, 32 rows/block)
    fused_attn<<<dim3(2048), 512, 0, stream>>>(FV, Mhi, Mlo, ctx, W);
}

// Round 3
// 662.753 us; speedup vs baseline: 2.1291x; 2.1291x over previous
//
#include <hip/hip_runtime.h>

// Problem constants: B=N=256, D=S=1024
// out = [ctx 256*1024 fp32 ; W 256*256*1024 fp32]

typedef _Float16 half8 __attribute__((ext_vector_type(8)));
typedef float floatx16 __attribute__((ext_vector_type(16)));

static __device__ __forceinline__ void split_f32(float x, _Float16& hi, _Float16& lo) {
    _Float16 h = (_Float16)x;
    hi = h;
    lo = (_Float16)(x - (float)h);
}

// ---------------------------------------------------------------------------
// Small GEMM: C[M,N] = A[M,K] @ B, fp32 in, hi/lo fp16 split on BOTH operands
// (3 MFMAs) for near-fp32 accuracy. BT=true: B stored [N,K] (contract fast dim,
// direct staging). BT=false: B stored [K,N] (transpose staging).
// OUT_HILO=false -> write fp32 C. OUT_HILO=true -> write hi/lo fp16 pair.
// Tile 64x64, 256 threads (4 waves as 2x2 of 32x32), BK=32.
// ---------------------------------------------------------------------------
template <bool BT, bool OUT_HILO>
__global__ __launch_bounds__(256, 2) void gemm_small(
    const float* __restrict__ Ag, const float* __restrict__ Bg,
    float* __restrict__ Cf, _Float16* __restrict__ Chi, _Float16* __restrict__ Clo,
    int Kdim, int Ndim)
{
    __shared__ __align__(16) _Float16 AsHi[4 * 64 * 8];
    __shared__ __align__(16) _Float16 AsLo[4 * 64 * 8];
    __shared__ __align__(16) _Float16 BsHi[4 * 64 * 8];
    __shared__ __align__(16) _Float16 BsLo[4 * 64 * 8];

    const int tid  = threadIdx.x;
    const int lane = tid & 63;
    const int wave = tid >> 6;
    const int wy = wave >> 1, wx = wave & 1;
    const int l31 = lane & 31, l5 = lane >> 5;
    const int m0 = blockIdx.y * 64, n0 = blockIdx.x * 64;

    floatx16 acc;
#pragma unroll
    for (int j = 0; j < 16; ++j) acc[j] = 0.0f;

    const int sA_m  = tid >> 2;  // 0..63 (row for A / row-of-B for BT)
    const int sA_kg = tid & 3;   // 0..3
    const int sB_n  = tid & 63;  // NN staging: n (coalesced)
    const int sB_kg = tid >> 6;  // NN staging: kg

    const int nkt = Kdim / 32;
#pragma unroll 1
    for (int kt = 0; kt < nkt; ++kt) {
        __syncthreads();
        {   // stage A chunk [32k x 64m] -> [kg][m][8] hi/lo
            const float* src = Ag + (size_t)(m0 + sA_m) * Kdim + kt * 32 + sA_kg * 8;
            half8 hi, lo;
#pragma unroll
            for (int j = 0; j < 8; ++j) {
                _Float16 h, l;
                split_f32(src[j], h, l);
                hi[j] = h; lo[j] = l;
            }
            *(half8*)&AsHi[(sA_kg * 64 + sA_m) * 8] = hi;
            *(half8*)&AsLo[(sA_kg * 64 + sA_m) * 8] = lo;
        }
        if constexpr (BT) {
            const float* src = Bg + (size_t)(n0 + sA_m) * Kdim + kt * 32 + sA_kg * 8;
            half8 hi, lo;
#pragma unroll
            for (int j = 0; j < 8; ++j) {
                _Float16 h, l;
                split_f32(src[j], h, l);
                hi[j] = h; lo[j] = l;
            }
            *(half8*)&BsHi[(sA_kg * 64 + sA_m) * 8] = hi;
            *(half8*)&BsLo[(sA_kg * 64 + sA_m) * 8] = lo;
        } else {
            const float* src = Bg + (size_t)(kt * 32 + sB_kg * 8) * Ndim + n0 + sB_n;
            half8 hi, lo;
#pragma unroll
            for (int j = 0; j < 8; ++j) {
                _Float16 h, l;
                split_f32(src[(size_t)j * Ndim], h, l);
                hi[j] = h; lo[j] = l;
            }
            *(half8*)&BsHi[(sB_kg * 64 + sB_n) * 8] = hi;
            *(half8*)&BsLo[(sB_kg * 64 + sB_n) * 8] = lo;
        }
        __syncthreads();
#pragma unroll
        for (int ks = 0; ks < 2; ++ks) {
            const int kg = ks * 2 + l5;
            const half8 ah = *(half8*)&AsHi[(kg * 64 + wy * 32 + l31) * 8];
            const half8 al = *(half8*)&AsLo[(kg * 64 + wy * 32 + l31) * 8];
            const half8 bh = *(half8*)&BsHi[(kg * 64 + wx * 32 + l31) * 8];
            const half8 bl = *(half8*)&BsLo[(kg * 64 + wx * 32 + l31) * 8];
            acc = __builtin_amdgcn_mfma_f32_32x32x16_f16(ah, bh, acc, 0, 0, 0);
            acc = __builtin_amdgcn_mfma_f32_32x32x16_f16(ah, bl, acc, 0, 0, 0);
            acc = __builtin_amdgcn_mfma_f32_32x32x16_f16(al, bh, acc, 0, 0, 0);
        }
    }

    // C/D layout (verified): col = lane&31, row = (reg&3) + 8*(reg>>2) + 4*(lane>>5)
#pragma unroll
    for (int reg = 0; reg < 16; ++reg) {
        const int row = m0 + wy * 32 + (reg & 3) + 8 * (reg >> 2) + 4 * l5;
        const int col = n0 + wx * 32 + l31;
        const float v = acc[reg];
        if constexpr (OUT_HILO) {
            _Float16 h, l;
            split_f32(v, h, l);
            Chi[(size_t)row * Ndim + col] = h;
            Clo[(size_t)row * Ndim + col] = l;
        } else {
            Cf[(size_t)row * Ndim + col] = v;
        }
    }
}

// ---------------------------------------------------------------------------
// Fused: per (i, b-tile of 64): logits = (Mhi+Mlo) @ fp16(FV[i])  (2 MFMAs),
// row softmax over d=1024, write W, accumulate ctx[i,d] += W * FV[i,b,d].
//
// Round-3 restructure: BARRIER-FREE K-loop, no LDS staging.
//  - R1's limiter was serialized fetch: 64 KB burst -> barrier -> full-latency
//    wait, with only ~400 cyc of lookahead (traffic was already minimal).
//  - R2's occupancy fix broke lockstep L2 sharing -> 4-6x traffic (reverted).
//  - FV[i] (1 MB) and M (256 KB) are L2-resident: B-fragments are loaded
//    coalesced DIRECTLY from global (fixed (nt,r): 32 lanes = 128 B contig),
//    A-fragments are 16 B contiguous half8 loads. Each of the 8 waves
//    free-runs with 64+ independent loads of ILP per chunk; latency
//    self-hides without barriers (guide common-mistake #7).
// Geometry unchanged from R1: 64 rows x 1024 d per block, 8 waves (2 wy x
// 4 wx), acc[8], 1024 blocks, XCD swizzle (4 sibling blocks of an i on one
// XCD; first toucher pulls chunk from HBM, siblings L2-hit).
// ---------------------------------------------------------------------------
__global__ __launch_bounds__(512, 2) void fused_attn(
    const float* __restrict__ FV, const _Float16* __restrict__ Mhi,
    const _Float16* __restrict__ Mlo, float* __restrict__ ctx,
    float* __restrict__ Wout)
{
    __shared__ __align__(16) float red1[64 * 4];
    __shared__ __align__(16) float red2[64 * 4];

    const int tid  = threadIdx.x;
    const int lane = tid & 63;
    const int wave = tid >> 6;
    const int wx = wave & 3;   // d-slice (256 cols)
    const int wy = wave >> 2;  // m-half (32 rows)
    const int l31 = lane & 31, l5 = lane >> 5;

    // XCD-aware swizzle: all 4 bt of an i share one XCD (R1's proven map).
    const int w   = blockIdx.x;   // 0..1023
    const int xcd = w & 7;
    const int k   = w >> 3;       // 0..127
    const int i   = (xcd << 5) + (k >> 2);  // 0..255
    const int bt  = k & 3;                  // 0..3

    const float* __restrict__ FVi = FV + (size_t)i * 256 * 1024;

    floatx16 acc[8];
#pragma unroll
    for (int nt = 0; nt < 8; ++nt)
#pragma unroll
        for (int j = 0; j < 16; ++j) acc[nt][j] = 0.0f;

    // A-fragment source: row (m) = bt*64 + wy*32 + l31, k = kt*16 + l5*8 + j
    const int arow = bt * 64 + wy * 32 + l31;
    const _Float16* __restrict__ Ah = Mhi + (size_t)arow * 256 + l5 * 8;
    const _Float16* __restrict__ Al = Mlo + (size_t)arow * 256 + l5 * 8;
    // B-fragment source: col (n=d) = wx*256 + nt*32 + l31, k-row = kt*16 + l5*8 + r
    const float* __restrict__ Bbase = FVi + (size_t)(l5 * 8) * 1024 + wx * 256 + l31;

#pragma unroll 1
    for (int kt = 0; kt < 16; ++kt) {
        const half8 ah = *(const half8*)(Ah + kt * 16);
        const half8 al = *(const half8*)(Al + kt * 16);
        const float* bp = Bbase + (size_t)kt * 16 * 1024;
#pragma unroll
        for (int nt = 0; nt < 8; ++nt) {
            half8 b;
#pragma unroll
            for (int r = 0; r < 8; ++r)
                b[r] = (_Float16)bp[nt * 32 + (size_t)r * 1024];
            acc[nt] = __builtin_amdgcn_mfma_f32_32x32x16_f16(ah, b, acc[nt], 0, 0, 0);
            acc[nt] = __builtin_amdgcn_mfma_f32_32x32x16_f16(al, b, acc[nt], 0, 0, 0);
        }
    }

    // ---- softmax over d (rows span 4 wx waves) ----
    // lane holds: col = wx*256 + nt*32 + l31 ; row = wy*32 + (reg&3)+8*(reg>>2)+4*l5
    float st[16];
#pragma unroll
    for (int reg = 0; reg < 16; ++reg) {
        float v = acc[0][reg];
#pragma unroll
        for (int nt = 1; nt < 8; ++nt) v = fmaxf(v, acc[nt][reg]);
#pragma unroll
        for (int off = 1; off < 32; off <<= 1) v = fmaxf(v, __shfl_xor(v, off));
        st[reg] = v;
    }
    if (l31 == 0) {
#pragma unroll
        for (int reg = 0; reg < 16; ++reg) {
            const int row = wy * 32 + (reg & 3) + 8 * (reg >> 2) + 4 * l5;
            red1[row * 4 + wx] = st[reg];
        }
    }
    __syncthreads();
    float rmax[16];
#pragma unroll
    for (int reg = 0; reg < 16; ++reg) {
        const int row = wy * 32 + (reg & 3) + 8 * (reg >> 2) + 4 * l5;
        const float4 m4 = *(const float4*)&red1[row * 4];
        rmax[reg] = fmaxf(fmaxf(m4.x, m4.y), fmaxf(m4.z, m4.w));
    }
#pragma unroll
    for (int reg = 0; reg < 16; ++reg) {
        float s = 0.0f;
#pragma unroll
        for (int nt = 0; nt < 8; ++nt) {
            const float p = __expf(acc[nt][reg] - rmax[reg]);
            acc[nt][reg] = p;
            s += p;
        }
#pragma unroll
        for (int off = 1; off < 32; off <<= 1) s += __shfl_xor(s, off);
        st[reg] = s;
    }
    if (l31 == 0) {
#pragma unroll
        for (int reg = 0; reg < 16; ++reg) {
            const int row = wy * 32 + (reg & 3) + 8 * (reg >> 2) + 4 * l5;
            red2[row * 4 + wx] = st[reg];
        }
    }
    __syncthreads();
    float inv[16];
#pragma unroll
    for (int reg = 0; reg < 16; ++reg) {
        const int row = wy * 32 + (reg & 3) + 8 * (reg >> 2) + 4 * l5;
        const float4 s4 = *(const float4*)&red2[row * 4];
        inv[reg] = 1.0f / (s4.x + s4.y + s4.z + s4.w);
    }

    // ---- write W, accumulate context ----
    float csum[8];
#pragma unroll
    for (int nt = 0; nt < 8; ++nt) csum[nt] = 0.0f;

    const int rowbase = bt * 64 + wy * 32;
#pragma unroll
    for (int nt = 0; nt < 8; ++nt) {
        const int col = wx * 256 + nt * 32 + l31;
#pragma unroll
        for (int reg = 0; reg < 16; ++reg) {
            const int row = (reg & 3) + 8 * (reg >> 2) + 4 * l5;
            const float wv = acc[nt][reg] * inv[reg];
            Wout[((size_t)(i * 256 + rowbase + row)) * 1024 + col] = wv;
            const float fv = FVi[(size_t)(rowbase + row) * 1024 + col];
            csum[nt] += wv * fv;
        }
    }
#pragma unroll
    for (int nt = 0; nt < 8; ++nt) {
        const float v = csum[nt] + __shfl_xor(csum[nt], 32);
        if (l5 == 0)
            atomicAdd(&ctx[(size_t)i * 1024 + wx * 256 + nt * 32 + l31], v);
    }
}

// ---------------------------------------------------------------------------
extern "C" void kernel_launch(void* const* d_in, const int* in_sizes, int n_in,
                              void* d_out, int out_size, void* d_ws, size_t ws_size,
                              hipStream_t stream)
{
    const float* FV    = (const float*)d_in[0];  // [256,256,1024]
    const float* state = (const float*)d_in[1];  // [256,1024]
    const float* Q     = (const float*)d_in[2];  // [1024,1024]
    const float* Km    = (const float*)d_in[3];  // [1024,256]

    float* out = (float*)d_out;
    float* ctx = out;                 // [256,1024]
    float* W   = out + 256 * 1024;    // [256,256,1024]

    char* ws = (char*)d_ws;
    float*    A1  = (float*)ws;                                 // [256,1024] fp32, 1 MB
    _Float16* Mhi = (_Float16*)(ws + (1 << 20));                // [256,256] f16, 128 KB
    _Float16* Mlo = (_Float16*)(ws + (1 << 20) + (1 << 17));    // [256,256] f16, 128 KB

    // ctx accumulated with atomics -> zero it
    (void)hipMemsetAsync(ctx, 0, 256 * 1024 * sizeof(float), stream);

    // A1 = state @ Q^T   (B stored [N,K]: Q[s,t], contract t)
    gemm_small<true, false><<<dim3(16, 4), 256, 0, stream>>>(
        state, Q, A1, nullptr, nullptr, 1024, 1024);

    // M = A1 @ K  -> hi/lo fp16   (B stored [K,N])
    gemm_small<false, true><<<dim3(4, 4), 256, 0, stream>>>(
        A1, Km, nullptr, Mhi, Mlo, 1024, 256);

    // fused logits -> softmax -> W + ctx (XCD-swizzled, barrier-free K-loop)
    fused_attn<<<dim3(1024), 512, 0, stream>>>(FV, Mhi, Mlo, ctx, W);
}